// Round 8
// baseline (945.614 us; speedup 1.0000x reference)
//
#include <hip/hip_runtime.h>
#include <hip/hip_bf16.h>
#include <math.h>
#include <stdint.h>

#define N_ROWS 8192
#define M_FACTS 8192
#define D_DIM 1024

typedef __bf16 bf16x8_t __attribute__((ext_vector_type(8)));
typedef __bf16 bf16x4_t __attribute__((ext_vector_type(4)));
typedef float f32x4_t __attribute__((ext_vector_type(4)));

#define BM 128
#define BN 128
#define BK 32
#define PADK 40  // legacy padded stride for fallback kernels

// Async global->LDS, 16B per lane. LDS dest = wave-uniform base + lane*16.
__device__ __forceinline__ void gload_lds16(const void* g, void* lds) {
  __builtin_amdgcn_global_load_lds(
      (__attribute__((address_space(1))) void*)(uintptr_t)g,
      (__attribute__((address_space(3))) void*)(uint32_t)(uintptr_t)lds,
      16, 0, 0);
}

// =========================================================================
// Precompute kernels
// =========================================================================

__global__ __launch_bounds__(256) void split_hi_lo(const float* __restrict__ X,
                                                   __bf16* __restrict__ H,
                                                   __bf16* __restrict__ L) {
  int i = blockIdx.x * 256 + threadIdx.x;
  float4 v = ((const float4*)X)[i];
  float f[4] = {v.x, v.y, v.z, v.w};
  bf16x4_t h, l;
#pragma unroll
  for (int q = 0; q < 4; q++) {
    __bf16 hh = (__bf16)f[q];
    h[q] = hh;
    l[q] = (__bf16)(f[q] - (float)hh);
  }
  ((bf16x4_t*)H)[i] = h;
  ((bf16x4_t*)L)[i] = l;
}

// E [N][1024] fp32 -> A2 [N][3072] bf16 = [Eh | El | Eh] (K-concat: the
// 3-product compensated GEMM becomes ONE standard bf16 GEMM with K=3072).
__global__ __launch_bounds__(256) void split_concat_E(const float* __restrict__ X,
                                                      __bf16* __restrict__ A2) {
  int idx = blockIdx.x * 256 + threadIdx.x;  // float4 index over N*1024/4
  int n = idx >> 8, d4 = idx & 255;
  float4 v = ((const float4*)X)[idx];
  float f[4] = {v.x, v.y, v.z, v.w};
  bf16x4_t h, l;
#pragma unroll
  for (int q = 0; q < 4; q++) {
    __bf16 hh = (__bf16)f[q];
    h[q] = hh;
    l[q] = (__bf16)(f[q] - (float)hh);
  }
  size_t base = (size_t)n * 3072 + d4 * 4;
  *(bf16x4_t*)(A2 + base) = h;
  *(bf16x4_t*)(A2 + base + 1024) = l;
  *(bf16x4_t*)(A2 + base + 2048) = h;
}

// F [M][1024] fp32 -> B2 [M][3072] bf16 = [Fh | Fh | Fl].
__global__ __launch_bounds__(256) void split_concat_F(const float* __restrict__ X,
                                                      __bf16* __restrict__ B2) {
  int idx = blockIdx.x * 256 + threadIdx.x;
  int m = idx >> 8, d4 = idx & 255;
  float4 v = ((const float4*)X)[idx];
  float f[4] = {v.x, v.y, v.z, v.w};
  bf16x4_t h, l;
#pragma unroll
  for (int q = 0; q < 4; q++) {
    __bf16 hh = (__bf16)f[q];
    h[q] = hh;
    l[q] = (__bf16)(f[q] - (float)hh);
  }
  size_t base = (size_t)m * 3072 + d4 * 4;
  *(bf16x4_t*)(B2 + base) = h;
  *(bf16x4_t*)(B2 + base + 1024) = h;
  *(bf16x4_t*)(B2 + base + 2048) = l;
}

// F fp32 [M][D] -> Ft bf16 [D][M]. 64x64 tiles; fp32 LDS tile stride 69.
__global__ __launch_bounds__(256) void transpose_f_bf16(const float* __restrict__ F,
                                                        __bf16* __restrict__ Ft) {
  __shared__ float t[64 * 69];
  const int tid = threadIdx.x;
  const int m0 = blockIdx.x * 64, d0 = blockIdx.y * 64;
#pragma unroll
  for (int p = 0; p < 4; p++) {
    int flat = p * 256 + tid;
    int m = flat >> 4, dq = flat & 15;
    float4 v = *(const float4*)(F + (size_t)(m0 + m) * D_DIM + d0 + dq * 4);
    t[(dq * 4 + 0) * 69 + m] = v.x;
    t[(dq * 4 + 1) * 69 + m] = v.y;
    t[(dq * 4 + 2) * 69 + m] = v.z;
    t[(dq * 4 + 3) * 69 + m] = v.w;
  }
  __syncthreads();
#pragma unroll
  for (int q = 0; q < 2; q++) {
    int id = q * 256 + tid;
    int d = id >> 3, c = id & 7;
    const float* row = t + d * 69 + c * 8;
    bf16x8_t o;
#pragma unroll
    for (int i = 0; i < 8; i++) o[i] = (__bf16)row[i];
    *(bf16x8_t*)(Ft + (size_t)(d0 + d) * M_FACTS + m0 + c * 8) = o;
  }
}

// =========================================================================
// Within-wave read-ahead pipelined B^T GEMM (round-6 kernel, measured 364us
// @ gemm1, passed). Used for gemm1 only.  C = A[*][K] * B[*][K]^T.
// BM=256, BN=CH*64. 512 thr = 8 waves (2M x 4N); per-wave C = 128 x CH*16.
// See round-6 notes; swizzle = pre-swizzled global source + XOR ds_read,
// 0 bank conflicts measured. Counted lgkmcnt read-ahead at half-tile
// granularity; one barrier per K-tile.
// =========================================================================
template <int CH>
__global__ __launch_bounds__(512, 2) void gemm_pipe(const __bf16* __restrict__ A,
                                                    const __bf16* __restrict__ B,
                                                    float* __restrict__ C,
                                                    int K, int lda, int ldb, int ldc) {
  constexpr int BNT = CH * 64;
  __shared__ __align__(16) __bf16 sA[2][256 * 64];
  __shared__ __align__(16) __bf16 sB[2][BNT * 64];
  const int tid = threadIdx.x;  // 0..511
  const int wave = tid >> 6, lane = tid & 63;
  const int wm = wave >> 2;   // 0..1  (A half: rows wm*128..+127)
  const int wn = wave & 3;    // 0..3  (C cols wn*CH*16)
  const int lrow = lane & 15, quad = lane >> 4;
  const int row0 = blockIdx.x * 256;
  const int col0 = blockIdx.y * BNT;

  // Staging: A 2048 granules (4/thread) + B CH*512 (CH/thread) per tile.
  auto STAGE = [&](int buf, int kt) {
    const int ko = kt * 64;
#pragma unroll
    for (int k = 0; k < 4; k++) {
      int g = tid + 512 * k;
      int sr = g >> 3;
      int so = ((g & 7) ^ (sr & 7)) << 3;
      gload_lds16(A + (size_t)(row0 + sr) * lda + ko + so, &sA[buf][g * 8]);
    }
#pragma unroll
    for (int k = 0; k < CH; k++) {
      int g = tid + 512 * k;
      int sr = g >> 3;
      int so = ((g & 7) ^ (sr & 7)) << 3;
      gload_lds16(B + (size_t)(col0 + sr) * ldb + ko + so, &sB[buf][g * 8]);
    }
  };

  // Unit frag read: 8 A-frags + CH B-frags for one ks half.
  auto RD_UNIT = [&](const __bf16* lA, const __bf16* lB, int ks,
                     bf16x8_t (&af)[8], bf16x8_t (&bfv)[CH]) {
#pragma unroll
    for (int rf = 0; rf < 8; ++rf) {
      const int r = wm * 128 + rf * 16 + lrow;
      af[rf] = *(const bf16x8_t*)(lA + r * 64 + (((ks * 4 + quad) ^ (r & 7)) << 3));
    }
#pragma unroll
    for (int cf = 0; cf < CH; ++cf) {
      const int c = wn * (CH * 16) + cf * 16 + lrow;
      bfv[cf] = *(const bf16x8_t*)(lB + c * 64 + (((ks * 4 + quad) ^ (c & 7)) << 3));
    }
  };

  f32x4_t acc[8][CH];
#pragma unroll
  for (int i = 0; i < 8; i++)
#pragma unroll
    for (int j = 0; j < CH; j++) acc[i][j] = (f32x4_t){0.f, 0.f, 0.f, 0.f};

  auto MM_UNIT = [&](bf16x8_t (&af)[8], bf16x8_t (&bfv)[CH]) {
    __builtin_amdgcn_s_setprio(1);
#pragma unroll
    for (int rf = 0; rf < 8; ++rf)
#pragma unroll
      for (int cf = 0; cf < CH; ++cf)
        acc[rf][cf] = __builtin_amdgcn_mfma_f32_16x16x32_bf16(af[rf], bfv[cf],
                                                              acc[rf][cf], 0, 0, 0);
    __builtin_amdgcn_s_setprio(0);
  };

  const int nkt = K >> 6;  // >= 2 for all call sites

  // Prologue: stage tiles 0,1; wait tile 0 only (tile 1's stay in flight).
  STAGE(0, 0);
  STAGE(1, 1);
  if constexpr (CH == 4)
    asm volatile("s_waitcnt vmcnt(8)" ::: "memory");
  else
    asm volatile("s_waitcnt vmcnt(6)" ::: "memory");
  __builtin_amdgcn_s_barrier();
  __builtin_amdgcn_sched_barrier(0);

  bf16x8_t aU[8], bU[CH];  // ks=0 frag set
  bf16x8_t aV[8], bV[CH];  // ks=1 frag set
  RD_UNIT(&sA[0][0], &sB[0][0], 0, aU, bU);  // frags(0, ks0)

  for (int t = 0; t < nkt; ++t) {
    const int cur = t & 1;
    const __bf16* lA = &sA[cur][0];
    const __bf16* lB = &sB[cur][0];

    // 1. read frags(t, ks1) -- serviced under MFMA-A window
    RD_UNIT(lA, lB, 1, aV, bV);
    // 2. counted wait: frags(t, ks0) ready, the new reads stay outstanding
    if constexpr (CH == 4)
      asm volatile("s_waitcnt lgkmcnt(12)" ::: "memory");
    else
      asm volatile("s_waitcnt lgkmcnt(10)" ::: "memory");
    __builtin_amdgcn_sched_barrier(0);
    // 3. MFMA unit (t, ks0)
    MM_UNIT(aU, bU);
    __builtin_amdgcn_sched_barrier(0);
    // 4. S(t+1) stages complete (issued a full tile ago); ks1 frags landed
    asm volatile("s_waitcnt vmcnt(0)" ::: "memory");
    asm volatile("s_waitcnt lgkmcnt(0)" ::: "memory");
    __builtin_amdgcn_sched_barrier(0);
    // 5. publish S(t+1); WAR-gate the stage into S(t)
    __builtin_amdgcn_s_barrier();
    __builtin_amdgcn_sched_barrier(0);
    // 6. stage tile t+2 into the dead slot S(t)
    if (t + 2 < nkt) STAGE(cur, t + 2);
    // 7. read frags(t+1, ks0) -- serviced under MFMA-B window
    if (t + 1 < nkt) RD_UNIT(&sA[cur ^ 1][0], &sB[cur ^ 1][0], 0, aU, bU);
    // 9. MFMA unit (t, ks1): frags already drained at 4 -> no wait
    MM_UNIT(aV, bV);
  }

  // Epilogue: C/D frag layout col=lane&15, row=(lane>>4)*4+reg.
#pragma unroll
  for (int rf = 0; rf < 8; ++rf) {
    const int rbase = row0 + wm * 128 + rf * 16 + quad * 4;
#pragma unroll
    for (int cf = 0; cf < CH; ++cf) {
      const int c = col0 + wn * (CH * 16) + cf * 16 + lrow;
#pragma unroll
      for (int r = 0; r < 4; ++r) C[(size_t)(rbase + r) * ldc + c] = acc[rf][cf][r];
    }
  }
}

// =========================================================================
// GEMM1 fast (t2-tier fallback): energy = Eh*Fh^T + Eh*Fl^T + El*Fh^T.
// =========================================================================
__global__ __launch_bounds__(256) void gemm1_fast(const __bf16* __restrict__ Eh,
                                                  const __bf16* __restrict__ El,
                                                  const __bf16* __restrict__ Fh,
                                                  const __bf16* __restrict__ Fl,
                                                  float* __restrict__ C,
                                                  int row_base) {
  __shared__ __bf16 sAh[BM * BK], sAl[BM * BK], sBh[BN * BK], sBl[BN * BK];
  const int tid = threadIdx.x;
  const int wave = tid >> 6, lane = tid & 63;
  const int row0 = row_base + blockIdx.x * BM, col0 = blockIdx.y * BN;
  const int wm = wave >> 1, wn = wave & 1;
  const int lrow = lane & 15, quad = lane >> 4;

  f32x4_t acc[4][4];
#pragma unroll
  for (int i = 0; i < 4; i++)
#pragma unroll
    for (int j = 0; j < 4; j++) acc[i][j] = (f32x4_t){0.f, 0.f, 0.f, 0.f};

  for (int k0 = 0; k0 < D_DIM; k0 += BK) {
#pragma unroll
    for (int r = 0; r < 2; r++) {
      int c = (r * 4 + wave) * 64 + lane;
      int row = c >> 2;
      int ko = (c & 3) << 3;
      size_t ga = (size_t)(row0 + row) * D_DIM + k0 + ko;
      size_t gb = (size_t)(col0 + row) * D_DIM + k0 + ko;
      gload_lds16(Eh + ga, sAh + c * 8);
      gload_lds16(El + ga, sAl + c * 8);
      gload_lds16(Fh + gb, sBh + c * 8);
      gload_lds16(Fl + gb, sBl + c * 8);
    }
    __syncthreads();

    bf16x8_t ah[4], al[4], bh[4], bl[4];
#pragma unroll
    for (int i = 0; i < 4; i++) {
      int ra = (wm * 64 + i * 16 + lrow) * BK + quad * 8;
      ah[i] = *(const bf16x8_t*)(sAh + ra);
      al[i] = *(const bf16x8_t*)(sAl + ra);
      int rb = (wn * 64 + i * 16 + lrow) * BK + quad * 8;
      bh[i] = *(const bf16x8_t*)(sBh + rb);
      bl[i] = *(const bf16x8_t*)(sBl + rb);
    }
#pragma unroll
    for (int i = 0; i < 4; i++)
#pragma unroll
      for (int j = 0; j < 4; j++) {
        acc[i][j] = __builtin_amdgcn_mfma_f32_16x16x32_bf16(ah[i], bh[j], acc[i][j], 0, 0, 0);
        acc[i][j] = __builtin_amdgcn_mfma_f32_16x16x32_bf16(ah[i], bl[j], acc[i][j], 0, 0, 0);
        acc[i][j] = __builtin_amdgcn_mfma_f32_16x16x32_bf16(al[i], bh[j], acc[i][j], 0, 0, 0);
      }
    __syncthreads();
  }

#pragma unroll
  for (int i = 0; i < 4; i++) {
    int rbase = row0 + wm * 64 + i * 16 + quad * 4;
#pragma unroll
    for (int j = 0; j < 4; j++) {
      int c = col0 + wn * 64 + j * 16 + lrow;
#pragma unroll
      for (int r = 0; r < 4; r++) C[(size_t)(rbase + r) * M_FACTS + c] = acc[i][j][r];
    }
  }
}

// =========================================================================
// GEMM2 register-staged double buffer (measured 205us @ full grid, round 0
// -- the best gemm2 of the session; 2 blocks/CU give inter-block overlap
// that covers the serial LDS+MFMA gaps, and 128^2 tiles keep the Wb panel
// L2-resident per XCD).
// =========================================================================
__global__ __launch_bounds__(256) void gemm2_reg(const __bf16* __restrict__ Wb,
                                                 const __bf16* __restrict__ Ft,
                                                 float* __restrict__ O,
                                                 int out_row0) {
  __shared__ __bf16 sW[2][BM * BK];
  __shared__ __bf16 sF[2][BN * BK];
  const int tid = threadIdx.x;
  const int wave = tid >> 6, lane = tid & 63;
  const int row0 = blockIdx.x * BM;  // n tile (fast axis -> XCD = n%8)
  const int col0 = blockIdx.y * BN;  // d tile
  const int wm = wave >> 1, wn = wave & 1;
  const int lrow = lane & 15, quad = lane >> 4;

  const int id0 = wave * 64 + lane;
  const int r0 = id0 >> 2, c0 = (id0 & 3) << 3;
  const int id1 = id0 + 256;
  const int r1 = id1 >> 2, c1 = (id1 & 3) << 3;

  const __bf16* gW = Wb + (size_t)row0 * M_FACTS;
  const __bf16* gF = Ft + (size_t)col0 * M_FACTS;

  f32x4_t acc[4][4];
#pragma unroll
  for (int i = 0; i < 4; i++)
#pragma unroll
    for (int j = 0; j < 4; j++) acc[i][j] = (f32x4_t){0.f, 0.f, 0.f, 0.f};

  bf16x8_t rW0, rW1, rF0, rF1;
  rW0 = *(const bf16x8_t*)(gW + (size_t)r0 * M_FACTS + c0);
  rW1 = *(const bf16x8_t*)(gW + (size_t)r1 * M_FACTS + c1);
  rF0 = *(const bf16x8_t*)(gF + (size_t)r0 * M_FACTS + c0);
  rF1 = *(const bf16x8_t*)(gF + (size_t)r1 * M_FACTS + c1);
  *(bf16x8_t*)(&sW[0][id0 * 8]) = rW0;
  *(bf16x8_t*)(&sW[0][id1 * 8]) = rW1;
  *(bf16x8_t*)(&sF[0][id0 * 8]) = rF0;
  *(bf16x8_t*)(&sF[0][id1 * 8]) = rF1;
  rW0 = *(const bf16x8_t*)(gW + (size_t)r0 * M_FACTS + BK + c0);
  rW1 = *(const bf16x8_t*)(gW + (size_t)r1 * M_FACTS + BK + c1);
  rF0 = *(const bf16x8_t*)(gF + (size_t)r0 * M_FACTS + BK + c0);
  rF1 = *(const bf16x8_t*)(gF + (size_t)r1 * M_FACTS + BK + c1);
  __syncthreads();

  const int NT = M_FACTS / BK;  // 256
  for (int it = 0; it < NT; it++) {
    const int cur = it & 1;
    bf16x8_t a[4], b[4];
#pragma unroll
    for (int i = 0; i < 4; i++) {
      a[i] = *(const bf16x8_t*)(&sW[cur][(wm * 64 + i * 16 + lrow) * BK + quad * 8]);
      b[i] = *(const bf16x8_t*)(&sF[cur][(wn * 64 + i * 16 + lrow) * BK + quad * 8]);
    }
#pragma unroll
    for (int i = 0; i < 4; i++)
#pragma unroll
      for (int j = 0; j < 4; j++)
        acc[i][j] = __builtin_amdgcn_mfma_f32_16x16x32_bf16(a[i], b[j], acc[i][j], 0, 0, 0);

    __syncthreads();
    if (it + 1 < NT) {
      const int nxt = cur ^ 1;
      *(bf16x8_t*)(&sW[nxt][id0 * 8]) = rW0;
      *(bf16x8_t*)(&sW[nxt][id1 * 8]) = rW1;
      *(bf16x8_t*)(&sF[nxt][id0 * 8]) = rF0;
      *(bf16x8_t*)(&sF[nxt][id1 * 8]) = rF1;
      if (it + 2 < NT) {
        const int ko = (it + 2) * BK;
        rW0 = *(const bf16x8_t*)(gW + (size_t)r0 * M_FACTS + ko + c0);
        rW1 = *(const bf16x8_t*)(gW + (size_t)r1 * M_FACTS + ko + c1);
        rF0 = *(const bf16x8_t*)(gF + (size_t)r0 * M_FACTS + ko + c0);
        rF1 = *(const bf16x8_t*)(gF + (size_t)r1 * M_FACTS + ko + c1);
      }
      __syncthreads();
    }
  }

#pragma unroll
  for (int i = 0; i < 4; i++) {
    int rbase = out_row0 + row0 + wm * 64 + i * 16 + quad * 4;
#pragma unroll
    for (int j = 0; j < 4; j++) {
      int c = col0 + wn * 64 + j * 16 + lrow;
#pragma unroll
      for (int r = 0; r < 4; r++) O[(size_t)(rbase + r) * D_DIM + c] = acc[i][j][r];
    }
  }
}

// GEMM2 mid fallback: A = W fp32 (convert in staging), B = Ft via async.
__global__ __launch_bounds__(256) void gemm2_mid(const float* __restrict__ W,
                                                 const __bf16* __restrict__ Ft,
                                                 float* __restrict__ O) {
  __shared__ __bf16 sW[BM * BK], sF[BN * BK];
  const int tid = threadIdx.x;
  const int wave = tid >> 6, lane = tid & 63;
  const int row0 = blockIdx.x * BM, col0 = blockIdx.y * BN;
  const int wm = wave >> 1, wn = wave & 1;
  const int lrow = lane & 15, quad = lane >> 4;

  f32x4_t acc[4][4];
#pragma unroll
  for (int i = 0; i < 4; i++)
#pragma unroll
    for (int j = 0; j < 4; j++) acc[i][j] = (f32x4_t){0.f, 0.f, 0.f, 0.f};

  for (int k0 = 0; k0 < M_FACTS; k0 += BK) {
#pragma unroll
    for (int r = 0; r < 2; r++) {
      int c = (r * 4 + wave) * 64 + lane;
      int row = c >> 2;
      int ko = (c & 3) << 3;
      gload_lds16(Ft + (size_t)(col0 + row) * M_FACTS + k0 + ko, sF + c * 8);
    }
#pragma unroll
    for (int it = 0; it < 4; it++) {
      int flat = it * 256 + tid;
      int r = flat >> 3, q = flat & 7;
      float4 v = *(const float4*)(W + (size_t)(row0 + r) * M_FACTS + k0 + q * 4);
      bf16x4_t h;
      h[0] = (__bf16)v.x;
      h[1] = (__bf16)v.y;
      h[2] = (__bf16)v.z;
      h[3] = (__bf16)v.w;
      *(bf16x4_t*)(sW + r * BK + q * 4) = h;
    }
    __syncthreads();

    bf16x8_t a[4], b[4];
#pragma unroll
    for (int i = 0; i < 4; i++) {
      a[i] = *(const bf16x8_t*)(sW + (wm * 64 + i * 16 + lrow) * BK + quad * 8);
      b[i] = *(const bf16x8_t*)(sF + (wn * 64 + i * 16 + lrow) * BK + quad * 8);
    }
#pragma unroll
    for (int i = 0; i < 4; i++)
#pragma unroll
      for (int j = 0; j < 4; j++)
        acc[i][j] = __builtin_amdgcn_mfma_f32_16x16x32_bf16(a[i], b[j], acc[i][j], 0, 0, 0);
    __syncthreads();
  }

#pragma unroll
  for (int i = 0; i < 4; i++) {
    int rbase = row0 + wm * 64 + i * 16 + quad * 4;
#pragma unroll
    for (int j = 0; j < 4; j++) {
      int c = col0 + wn * 64 + j * 16 + lrow;
#pragma unroll
      for (int r = 0; r < 4; r++) O[(size_t)(rbase + r) * D_DIM + c] = acc[i][j][r];
    }
  }
}

// =========================================================================
// Softmax (optionally emitting bf16 copy of weights)
// =========================================================================
template <bool EMIT_BF16>
__global__ __launch_bounds__(256) void softmax_rows_t(float* __restrict__ W,
                                                      __bf16* __restrict__ Wb) {
  __shared__ float red[8];
  const int tid = threadIdx.x;
  float* p = W + (size_t)blockIdx.x * M_FACTS;

  float4 v[8];
  float mx = -3.4e38f;
#pragma unroll
  for (int i = 0; i < 8; i++) {
    v[i] = *(const float4*)(p + (size_t)(i * 256 + tid) * 4);
    mx = fmaxf(mx, fmaxf(fmaxf(v[i].x, v[i].y), fmaxf(v[i].z, v[i].w)));
  }
#pragma unroll
  for (int off = 32; off >= 1; off >>= 1) mx = fmaxf(mx, __shfl_xor(mx, off));
  const int wave = tid >> 6, lane = tid & 63;
  if (lane == 0) red[wave] = mx;
  __syncthreads();
  mx = fmaxf(fmaxf(red[0], red[1]), fmaxf(red[2], red[3]));

  float s = 0.f;
#pragma unroll
  for (int i = 0; i < 8; i++) {
    v[i].x = __expf(v[i].x - mx);
    v[i].y = __expf(v[i].y - mx);
    v[i].z = __expf(v[i].z - mx);
    v[i].w = __expf(v[i].w - mx);
    s += v[i].x + v[i].y + v[i].z + v[i].w;
  }
#pragma unroll
  for (int off = 32; off >= 1; off >>= 1) s += __shfl_xor(s, off);
  if (lane == 0) red[4 + wave] = s;
  __syncthreads();
  s = red[4] + red[5] + red[6] + red[7];
  float inv = 1.0f / s;
  __bf16* pb = EMIT_BF16 ? (Wb + (size_t)blockIdx.x * M_FACTS) : nullptr;
#pragma unroll
  for (int i = 0; i < 8; i++) {
    v[i].x *= inv;
    v[i].y *= inv;
    v[i].z *= inv;
    v[i].w *= inv;
    *(float4*)(p + (size_t)(i * 256 + tid) * 4) = v[i];
    if (EMIT_BF16) {
      bf16x4_t h;
      h[0] = (__bf16)v[i].x;
      h[1] = (__bf16)v[i].y;
      h[2] = (__bf16)v[i].z;
      h[3] = (__bf16)v[i].w;
      *(bf16x4_t*)(pb + (size_t)(i * 256 + tid) * 4) = h;
    }
  }
}

// =========================================================================
// Lowest-tier fallback kernels (ws < 80 MiB)
// =========================================================================
__global__ __launch_bounds__(256) void gemm1_energy(const float* __restrict__ A,
                                                    const float* __restrict__ B,
                                                    float* __restrict__ C) {
  __shared__ __align__(16) __bf16 sAh[BM * PADK];
  __shared__ __align__(16) __bf16 sAl[BM * PADK];
  __shared__ __align__(16) __bf16 sBh[BN * PADK];
  __shared__ __align__(16) __bf16 sBl[BN * PADK];

  const int tid = threadIdx.x;
  const int row0 = blockIdx.x * BM, col0 = blockIdx.y * BN;
  const int wave = tid >> 6, lane = tid & 63;
  const int wm = wave >> 1, wn = wave & 1;
  const int lrow = lane & 15, quad = lane >> 4;

  f32x4_t acc[4][4];
#pragma unroll
  for (int i = 0; i < 4; i++)
#pragma unroll
    for (int j = 0; j < 4; j++) acc[i][j] = (f32x4_t){0.f, 0.f, 0.f, 0.f};

  for (int k0 = 0; k0 < D_DIM; k0 += BK) {
    __syncthreads();
#pragma unroll
    for (int it = 0; it < 4; it++) {
      int flat = it * 256 + tid;
      int r = flat >> 3, kq = flat & 7;
      float4 va = *(const float4*)(A + (size_t)(row0 + r) * D_DIM + k0 + kq * 4);
      float4 vb = *(const float4*)(B + (size_t)(col0 + r) * D_DIM + k0 + kq * 4);
      float fa[4] = {va.x, va.y, va.z, va.w};
      float fb[4] = {vb.x, vb.y, vb.z, vb.w};
      bf16x4_t ah, al, bh, bl;
#pragma unroll
      for (int q = 0; q < 4; q++) {
        __bf16 h = (__bf16)fa[q];
        ah[q] = h;
        al[q] = (__bf16)(fa[q] - (float)h);
        __bf16 g = (__bf16)fb[q];
        bh[q] = g;
        bl[q] = (__bf16)(fb[q] - (float)g);
      }
      *(bf16x4_t*)(sAh + r * PADK + kq * 4) = ah;
      *(bf16x4_t*)(sAl + r * PADK + kq * 4) = al;
      *(bf16x4_t*)(sBh + r * PADK + kq * 4) = bh;
      *(bf16x4_t*)(sBl + r * PADK + kq * 4) = bl;
    }
    __syncthreads();

    bf16x8_t a_h[4], a_l[4], b_h[4], b_l[4];
#pragma unroll
    for (int i = 0; i < 4; i++) {
      int ra = wm * 64 + i * 16 + lrow;
      a_h[i] = *(const bf16x8_t*)(sAh + ra * PADK + quad * 8);
      a_l[i] = *(const bf16x8_t*)(sAl + ra * PADK + quad * 8);
      int rb = wn * 64 + i * 16 + lrow;
      b_h[i] = *(const bf16x8_t*)(sBh + rb * PADK + quad * 8);
      b_l[i] = *(const bf16x8_t*)(sBl + rb * PADK + quad * 8);
    }
#pragma unroll
    for (int i = 0; i < 4; i++)
#pragma unroll
      for (int j = 0; j < 4; j++) {
        acc[i][j] = __builtin_amdgcn_mfma_f32_16x16x32_bf16(a_h[i], b_h[j], acc[i][j], 0, 0, 0);
        acc[i][j] = __builtin_amdgcn_mfma_f32_16x16x32_bf16(a_h[i], b_l[j], acc[i][j], 0, 0, 0);
        acc[i][j] = __builtin_amdgcn_mfma_f32_16x16x32_bf16(a_l[i], b_h[j], acc[i][j], 0, 0, 0);
      }
  }

#pragma unroll
  for (int i = 0; i < 4; i++) {
    int rbase = row0 + wm * 64 + i * 16 + quad * 4;
#pragma unroll
    for (int j = 0; j < 4; j++) {
      int c = col0 + wn * 64 + j * 16 + lrow;
#pragma unroll
      for (int r = 0; r < 4; r++) C[(size_t)(rbase + r) * M_FACTS + c] = acc[i][j][r];
    }
  }
}

__global__ __launch_bounds__(256) void gemm2_out(const float* __restrict__ W,
                                                 const float* __restrict__ F,
                                                 float* __restrict__ O) {
  __shared__ __align__(16) __bf16 sW[BM * PADK];
  __shared__ __align__(16) __bf16 sFt[BN * PADK];

  const int tid = threadIdx.x;
  const int row0 = blockIdx.x * BM, col0 = blockIdx.y * BN;
  const int wave = tid >> 6, lane = tid & 63;
  const int wm = wave >> 1, wn = wave & 1;
  const int lrow = lane & 15, quad = lane >> 4;

  f32x4_t acc[4][4];
#pragma unroll
  for (int i = 0; i < 4; i++)
#pragma unroll
    for (int j = 0; j < 4; j++) acc[i][j] = (f32x4_t){0.f, 0.f, 0.f, 0.f};

  for (int k0 = 0; k0 < M_FACTS; k0 += BK) {
    __syncthreads();
#pragma unroll
    for (int it = 0; it < 4; it++) {
      int flat = it * 256 + tid;
      int r = flat >> 3, kq = flat & 7;
      float4 v = *(const float4*)(W + (size_t)(row0 + r) * M_FACTS + k0 + kq * 4);
      bf16x4_t h;
      h[0] = (__bf16)v.x;
      h[1] = (__bf16)v.y;
      h[2] = (__bf16)v.z;
      h[3] = (__bf16)v.w;
      *(bf16x4_t*)(sW + r * PADK + kq * 4) = h;
    }
#pragma unroll
    for (int it = 0; it < 4; it++) {
      int flat = it * 256 + tid;
      int m = flat >> 5, dq = flat & 31;
      float4 v = *(const float4*)(F + (size_t)(k0 + m) * D_DIM + col0 + dq * 4);
      sFt[(dq * 4 + 0) * PADK + m] = (__bf16)v.x;
      sFt[(dq * 4 + 1) * PADK + m] = (__bf16)v.y;
      sFt[(dq * 4 + 2) * PADK + m] = (__bf16)v.z;
      sFt[(dq * 4 + 3) * PADK + m] = (__bf16)v.w;
    }
    __syncthreads();

    bf16x8_t a[4], b[4];
#pragma unroll
    for (int i = 0; i < 4; i++) {
      a[i] = *(const bf16x8_t*)(sW + (wm * 64 + i * 16 + lrow) * PADK + quad * 8);
      b[i] = *(const bf16x8_t*)(sFt + (wn * 64 + i * 16 + lrow) * PADK + quad * 8);
    }
#pragma unroll
    for (int i = 0; i < 4; i++)
#pragma unroll
      for (int j = 0; j < 4; j++)
        acc[i][j] = __builtin_amdgcn_mfma_f32_16x16x32_bf16(a[i], b[j], acc[i][j], 0, 0, 0);
  }

#pragma unroll
  for (int i = 0; i < 4; i++) {
    int rbase = row0 + wm * 64 + i * 16 + quad * 4;
#pragma unroll
    for (int j = 0; j < 4; j++) {
      int c = col0 + wn * 64 + j * 16 + lrow;
#pragma unroll
      for (int r = 0; r < 4; r++) O[(size_t)(rbase + r) * D_DIM + c] = acc[i][j][r];
    }
  }
}

// =========================================================================
extern "C" void kernel_launch(void* const* d_in, const int* in_sizes, int n_in,
                              void* d_out, int out_size, void* d_ws, size_t ws_size,
                              hipStream_t stream) {
  const float* E = (const float*)d_in[0];  // [N, D]
  const float* F = (const float*)d_in[1];  // [M, D]
  float* outputs = (float*)d_out;                           // [N, D]
  float* weights = (float*)d_out + (size_t)N_ROWS * D_DIM;  // [N, M]

  const size_t MB = 1ull << 20;
  char* ws = (char*)d_ws;

  const bool t1 = ws_size >= 144 * MB;
  const bool t2 = !t1 && ws_size >= 80 * MB;
  const bool hasFtOnly = !t1 && !t2 && ws_size >= 16 * MB;

  if (t1) {
    // Layout: Ft 0-16MB | A2 16-64MB | B2 64-112MB | Wb 16-144MB (aliases
    // dead A2/B2 after gemm1).
    __bf16* Ft = (__bf16*)(ws + 0 * MB);
    __bf16* A2 = (__bf16*)(ws + 16 * MB);
    __bf16* B2 = (__bf16*)(ws + 64 * MB);
    __bf16* Wb = (__bf16*)(ws + 16 * MB);

    transpose_f_bf16<<<dim3(M_FACTS / 64, D_DIM / 64), 256, 0, stream>>>(F, Ft);
    split_concat_E<<<dim3((N_ROWS * D_DIM) / 1024), 256, 0, stream>>>(E, A2);
    split_concat_F<<<dim3((M_FACTS * D_DIM) / 1024), 256, 0, stream>>>(F, B2);

    // gemm1: ONE bf16 GEMM, K=3072 (round-6 kernel, measured 364us).
    gemm_pipe<4><<<dim3(N_ROWS / 256, M_FACTS / 256), 512, 0, stream>>>(
        A2, B2, weights, 3072, 3072, 3072, M_FACTS);

    softmax_rows_t<true><<<dim3(N_ROWS), 256, 0, stream>>>(weights, Wb);

    // gemm2: round-0 gemm2_reg, full grid (64,8)=512 blocks = 2 blocks/CU
    // (measured 205us -- best gemm2 of the session; the big-tile 1-blk/CU
    // variants all regressed to ~400us, hidden by kernel-name collision).
    gemm2_reg<<<dim3(N_ROWS / BM, D_DIM / BN), 256, 0, stream>>>(Wb, Ft, outputs, 0);
  } else if (t2) {
    __bf16* Ft = (__bf16*)(ws + 0 * MB);
    __bf16* Eh = (__bf16*)(ws + 16 * MB);
    __bf16* El = (__bf16*)(ws + 32 * MB);
    __bf16* Fh = (__bf16*)(ws + 48 * MB);
    __bf16* Fl = (__bf16*)(ws + 64 * MB);
    __bf16* Wb = (__bf16*)(ws + 16 * MB);

    transpose_f_bf16<<<dim3(M_FACTS / 64, D_DIM / 64), 256, 0, stream>>>(F, Ft);
    split_hi_lo<<<dim3((N_ROWS * D_DIM) / 1024), 256, 0, stream>>>(E, Eh, El);
    split_hi_lo<<<dim3((M_FACTS * D_DIM) / 1024), 256, 0, stream>>>(F, Fh, Fl);
    gemm1_fast<<<dim3(N_ROWS / BM, M_FACTS / BN), 256, 0, stream>>>(Eh, El, Fh, Fl,
                                                                    weights, 0);
    const int HALF = N_ROWS / 2;
    for (int h = 0; h < 2; h++) {
      float* Wchunk = weights + (size_t)h * HALF * M_FACTS;
      softmax_rows_t<true><<<dim3(HALF), 256, 0, stream>>>(Wchunk, Wb);
      gemm2_reg<<<dim3(HALF / BM, D_DIM / BN), 256, 0, stream>>>(Wb, Ft, outputs, h * HALF);
    }
  } else {
    __bf16* Ft = (__bf16*)ws;  // 16 MiB
    if (hasFtOnly) {
      transpose_f_bf16<<<dim3(M_FACTS / 64, D_DIM / 64), 256, 0, stream>>>(F, Ft);
    }
    gemm1_energy<<<dim3(N_ROWS / BM, M_FACTS / BN), 256, 0, stream>>>(E, F, weights);
    softmax_rows_t<false><<<dim3(N_ROWS), 256, 0, stream>>>(weights, nullptr);
    if (hasFtOnly) {
      gemm2_mid<<<dim3(N_ROWS / BM, D_DIM / BN), 256, 0, stream>>>(weights, Ft, outputs);
    } else {
      gemm2_out<<<dim3(N_ROWS / BM, D_DIM / BN), 256, 0, stream>>>(weights, F, outputs);
    }
  }
}

// Round 9
// 897.506 us; speedup vs baseline: 1.0536x; 1.0536x over previous
//
#include <hip/hip_runtime.h>
#include <hip/hip_bf16.h>
#include <math.h>
#include <stdint.h>

#define N_ROWS 8192
#define M_FACTS 8192
#define D_DIM 1024

typedef __bf16 bf16x8_t __attribute__((ext_vector_type(8)));
typedef __bf16 bf16x4_t __attribute__((ext_vector_type(4)));
typedef float f32x4_t __attribute__((ext_vector_type(4)));

#define BM 128
#define BN 128
#define BK 32
#define PADK 40  // legacy padded stride for fallback kernels

// Async global->LDS, 16B per lane. LDS dest = wave-uniform base + lane*16.
__device__ __forceinline__ void gload_lds16(const void* g, void* lds) {
  __builtin_amdgcn_global_load_lds(
      (__attribute__((address_space(1))) void*)(uintptr_t)g,
      (__attribute__((address_space(3))) void*)(uint32_t)(uintptr_t)lds,
      16, 0, 0);
}

// =========================================================================
// Precompute kernels
// =========================================================================

__global__ __launch_bounds__(256) void split_hi_lo(const float* __restrict__ X,
                                                   __bf16* __restrict__ H,
                                                   __bf16* __restrict__ L) {
  int i = blockIdx.x * 256 + threadIdx.x;
  float4 v = ((const float4*)X)[i];
  float f[4] = {v.x, v.y, v.z, v.w};
  bf16x4_t h, l;
#pragma unroll
  for (int q = 0; q < 4; q++) {
    __bf16 hh = (__bf16)f[q];
    h[q] = hh;
    l[q] = (__bf16)(f[q] - (float)hh);
  }
  ((bf16x4_t*)H)[i] = h;
  ((bf16x4_t*)L)[i] = l;
}

// E [N][1024] fp32 -> A2 [N][3072] bf16 = [Eh | El | Eh] (K-concat: the
// 3-product compensated GEMM becomes ONE standard bf16 GEMM with K=3072).
__global__ __launch_bounds__(256) void split_concat_E(const float* __restrict__ X,
                                                      __bf16* __restrict__ A2) {
  int idx = blockIdx.x * 256 + threadIdx.x;  // float4 index over N*1024/4
  int n = idx >> 8, d4 = idx & 255;
  float4 v = ((const float4*)X)[idx];
  float f[4] = {v.x, v.y, v.z, v.w};
  bf16x4_t h, l;
#pragma unroll
  for (int q = 0; q < 4; q++) {
    __bf16 hh = (__bf16)f[q];
    h[q] = hh;
    l[q] = (__bf16)(f[q] - (float)hh);
  }
  size_t base = (size_t)n * 3072 + d4 * 4;
  *(bf16x4_t*)(A2 + base) = h;
  *(bf16x4_t*)(A2 + base + 1024) = l;
  *(bf16x4_t*)(A2 + base + 2048) = h;
}

// F [M][1024] fp32 -> B2 [M][3072] bf16 = [Fh | Fh | Fl].
__global__ __launch_bounds__(256) void split_concat_F(const float* __restrict__ X,
                                                      __bf16* __restrict__ B2) {
  int idx = blockIdx.x * 256 + threadIdx.x;
  int m = idx >> 8, d4 = idx & 255;
  float4 v = ((const float4*)X)[idx];
  float f[4] = {v.x, v.y, v.z, v.w};
  bf16x4_t h, l;
#pragma unroll
  for (int q = 0; q < 4; q++) {
    __bf16 hh = (__bf16)f[q];
    h[q] = hh;
    l[q] = (__bf16)(f[q] - (float)hh);
  }
  size_t base = (size_t)m * 3072 + d4 * 4;
  *(bf16x4_t*)(B2 + base) = h;
  *(bf16x4_t*)(B2 + base + 1024) = h;
  *(bf16x4_t*)(B2 + base + 2048) = l;
}

// F fp32 [M][D] -> Ft bf16 [D][M]. 64x64 tiles; fp32 LDS tile stride 69.
__global__ __launch_bounds__(256) void transpose_f_bf16(const float* __restrict__ F,
                                                        __bf16* __restrict__ Ft) {
  __shared__ float t[64 * 69];
  const int tid = threadIdx.x;
  const int m0 = blockIdx.x * 64, d0 = blockIdx.y * 64;
#pragma unroll
  for (int p = 0; p < 4; p++) {
    int flat = p * 256 + tid;
    int m = flat >> 4, dq = flat & 15;
    float4 v = *(const float4*)(F + (size_t)(m0 + m) * D_DIM + d0 + dq * 4);
    t[(dq * 4 + 0) * 69 + m] = v.x;
    t[(dq * 4 + 1) * 69 + m] = v.y;
    t[(dq * 4 + 2) * 69 + m] = v.z;
    t[(dq * 4 + 3) * 69 + m] = v.w;
  }
  __syncthreads();
#pragma unroll
  for (int q = 0; q < 2; q++) {
    int id = q * 256 + tid;
    int d = id >> 3, c = id & 7;
    const float* row = t + d * 69 + c * 8;
    bf16x8_t o;
#pragma unroll
    for (int i = 0; i < 8; i++) o[i] = (__bf16)row[i];
    *(bf16x8_t*)(Ft + (size_t)(d0 + d) * M_FACTS + m0 + c * 8) = o;
  }
}

// =========================================================================
// Within-wave read-ahead pipelined B^T GEMM (round-6 kernel, measured
// 364-368us @ gemm1 across 3 rounds). Used for gemm1 only.
// =========================================================================
template <int CH>
__global__ __launch_bounds__(512, 2) void gemm_pipe(const __bf16* __restrict__ A,
                                                    const __bf16* __restrict__ B,
                                                    float* __restrict__ C,
                                                    int K, int lda, int ldb, int ldc) {
  constexpr int BNT = CH * 64;
  __shared__ __align__(16) __bf16 sA[2][256 * 64];
  __shared__ __align__(16) __bf16 sB[2][BNT * 64];
  const int tid = threadIdx.x;  // 0..511
  const int wave = tid >> 6, lane = tid & 63;
  const int wm = wave >> 2;   // 0..1  (A half: rows wm*128..+127)
  const int wn = wave & 3;    // 0..3  (C cols wn*CH*16)
  const int lrow = lane & 15, quad = lane >> 4;
  const int row0 = blockIdx.x * 256;
  const int col0 = blockIdx.y * BNT;

  auto STAGE = [&](int buf, int kt) {
    const int ko = kt * 64;
#pragma unroll
    for (int k = 0; k < 4; k++) {
      int g = tid + 512 * k;
      int sr = g >> 3;
      int so = ((g & 7) ^ (sr & 7)) << 3;
      gload_lds16(A + (size_t)(row0 + sr) * lda + ko + so, &sA[buf][g * 8]);
    }
#pragma unroll
    for (int k = 0; k < CH; k++) {
      int g = tid + 512 * k;
      int sr = g >> 3;
      int so = ((g & 7) ^ (sr & 7)) << 3;
      gload_lds16(B + (size_t)(col0 + sr) * ldb + ko + so, &sB[buf][g * 8]);
    }
  };

  auto RD_UNIT = [&](const __bf16* lA, const __bf16* lB, int ks,
                     bf16x8_t (&af)[8], bf16x8_t (&bfv)[CH]) {
#pragma unroll
    for (int rf = 0; rf < 8; ++rf) {
      const int r = wm * 128 + rf * 16 + lrow;
      af[rf] = *(const bf16x8_t*)(lA + r * 64 + (((ks * 4 + quad) ^ (r & 7)) << 3));
    }
#pragma unroll
    for (int cf = 0; cf < CH; ++cf) {
      const int c = wn * (CH * 16) + cf * 16 + lrow;
      bfv[cf] = *(const bf16x8_t*)(lB + c * 64 + (((ks * 4 + quad) ^ (c & 7)) << 3));
    }
  };

  f32x4_t acc[8][CH];
#pragma unroll
  for (int i = 0; i < 8; i++)
#pragma unroll
    for (int j = 0; j < CH; j++) acc[i][j] = (f32x4_t){0.f, 0.f, 0.f, 0.f};

  auto MM_UNIT = [&](bf16x8_t (&af)[8], bf16x8_t (&bfv)[CH]) {
    __builtin_amdgcn_s_setprio(1);
#pragma unroll
    for (int rf = 0; rf < 8; ++rf)
#pragma unroll
      for (int cf = 0; cf < CH; ++cf)
        acc[rf][cf] = __builtin_amdgcn_mfma_f32_16x16x32_bf16(af[rf], bfv[cf],
                                                              acc[rf][cf], 0, 0, 0);
    __builtin_amdgcn_s_setprio(0);
  };

  const int nkt = K >> 6;  // >= 2 for all call sites

  STAGE(0, 0);
  STAGE(1, 1);
  if constexpr (CH == 4)
    asm volatile("s_waitcnt vmcnt(8)" ::: "memory");
  else
    asm volatile("s_waitcnt vmcnt(6)" ::: "memory");
  __builtin_amdgcn_s_barrier();
  __builtin_amdgcn_sched_barrier(0);

  bf16x8_t aU[8], bU[CH];  // ks=0 frag set
  bf16x8_t aV[8], bV[CH];  // ks=1 frag set
  RD_UNIT(&sA[0][0], &sB[0][0], 0, aU, bU);  // frags(0, ks0)

  for (int t = 0; t < nkt; ++t) {
    const int cur = t & 1;
    const __bf16* lA = &sA[cur][0];
    const __bf16* lB = &sB[cur][0];

    RD_UNIT(lA, lB, 1, aV, bV);
    if constexpr (CH == 4)
      asm volatile("s_waitcnt lgkmcnt(12)" ::: "memory");
    else
      asm volatile("s_waitcnt lgkmcnt(10)" ::: "memory");
    __builtin_amdgcn_sched_barrier(0);
    MM_UNIT(aU, bU);
    __builtin_amdgcn_sched_barrier(0);
    asm volatile("s_waitcnt vmcnt(0)" ::: "memory");
    asm volatile("s_waitcnt lgkmcnt(0)" ::: "memory");
    __builtin_amdgcn_sched_barrier(0);
    __builtin_amdgcn_s_barrier();
    __builtin_amdgcn_sched_barrier(0);
    if (t + 2 < nkt) STAGE(cur, t + 2);
    if (t + 1 < nkt) RD_UNIT(&sA[cur ^ 1][0], &sB[cur ^ 1][0], 0, aU, bU);
    MM_UNIT(aV, bV);
  }

#pragma unroll
  for (int rf = 0; rf < 8; ++rf) {
    const int rbase = row0 + wm * 128 + rf * 16 + quad * 4;
#pragma unroll
    for (int cf = 0; cf < CH; ++cf) {
      const int c = col0 + wn * (CH * 16) + cf * 16 + lrow;
#pragma unroll
      for (int r = 0; r < 4; ++r) C[(size_t)(rbase + r) * ldc + c] = acc[rf][cf][r];
    }
  }
}

// =========================================================================
// 3-slot-ring counted-vmcnt B^T GEMM (round-3 kernel, passed refcheck; at
// the gemm2 call site its implied dur was ~141us -- best gemm2 of the
// session under the corrected budget model C = pre+softmax+overhead = 375).
// BM=256, BN=128, BK=64. 512 thr = 8 waves (2M x 4N), per-wave C = 128x32.
// LDS = 3 ring slots x 48KB = 147KB -> 1 block/CU, 8 waves.
// Ring: compute tile t from slot t%3; during phase 0 stage tile t+2 into
// slot (t-1)%3; boundary s_waitcnt vmcnt(6) waits only tile t+1's loads
// (issued two tiles earlier) -- counted, never drains to 0 in-loop.
// =========================================================================
__global__ __launch_bounds__(512, 2) void gemm_ring(const __bf16* __restrict__ A,
                                                    const __bf16* __restrict__ B,
                                                    float* __restrict__ C,
                                                    int K, int lda, int ldb, int ldc) {
  __shared__ __align__(16) __bf16 sA[3][256 * 64];
  __shared__ __align__(16) __bf16 sB[3][128 * 64];
  const int tid = threadIdx.x;  // 0..511
  const int wave = tid >> 6, lane = tid & 63;
  const int wm = wave >> 2;   // 0..1  (A half: rows wm*128..+127)
  const int wn = wave & 3;    // 0..3  (C cols wn*32..+31)
  const int lrow = lane & 15, quad = lane >> 4;
  const int row0 = blockIdx.x * 256;
  const int col0 = blockIdx.y * 128;

  auto STAGE = [&](int slot, int kt) {
    const int ko = kt * 64;
#pragma unroll
    for (int k = 0; k < 4; k++) {
      int g = tid + 512 * k;
      int sr = g >> 3;
      int so = ((g & 7) ^ (sr & 7)) << 3;
      gload_lds16(A + (size_t)(row0 + sr) * lda + ko + so, &sA[slot][g * 8]);
    }
#pragma unroll
    for (int k = 0; k < 2; k++) {
      int g = tid + 512 * k;
      int sr = g >> 3;
      int so = ((g & 7) ^ (sr & 7)) << 3;
      gload_lds16(B + (size_t)(col0 + sr) * ldb + ko + so, &sB[slot][g * 8]);
    }
  };

  f32x4_t acc[8][2];
#pragma unroll
  for (int i = 0; i < 8; i++)
#pragma unroll
    for (int j = 0; j < 2; j++) acc[i][j] = (f32x4_t){0.f, 0.f, 0.f, 0.f};

  const int nkt = K >> 6;

  STAGE(0, 0);
  STAGE(1, 1);
  asm volatile("s_waitcnt vmcnt(6)" ::: "memory");
  __builtin_amdgcn_s_barrier();
  __builtin_amdgcn_sched_barrier(0);

  int slot = 0;
  for (int t = 0; t < nkt; ++t) {
    const __bf16* lA = &sA[slot][0];
    const __bf16* lB = &sB[slot][0];
    const int slot2 = (slot == 0) ? 2 : slot - 1;  // (t+2)%3

#pragma unroll
    for (int p = 0; p < 2; ++p) {  // p = rhalf (64-row sub-block of wave's half)
      bf16x8_t af[4][2], bfr[2][2];
#pragma unroll
      for (int rf = 0; rf < 4; ++rf) {
        const int r = wm * 128 + p * 64 + rf * 16 + lrow;
#pragma unroll
        for (int ks = 0; ks < 2; ++ks)
          af[rf][ks] = *(const bf16x8_t*)(lA + r * 64 + (((ks * 4 + quad) ^ (r & 7)) << 3));
      }
#pragma unroll
      for (int cf = 0; cf < 2; ++cf) {
        const int c = wn * 32 + cf * 16 + lrow;
#pragma unroll
        for (int ks = 0; ks < 2; ++ks)
          bfr[cf][ks] = *(const bf16x8_t*)(lB + c * 64 + (((ks * 4 + quad) ^ (c & 7)) << 3));
      }
      if (p == 0 && t + 2 < nkt) STAGE(slot2, t + 2);
      __builtin_amdgcn_s_setprio(1);
#pragma unroll
      for (int rf = 0; rf < 4; ++rf)
#pragma unroll
        for (int cf = 0; cf < 2; ++cf)
#pragma unroll
          for (int ks = 0; ks < 2; ++ks)
            acc[p * 4 + rf][cf] = __builtin_amdgcn_mfma_f32_16x16x32_bf16(
                af[rf][ks], bfr[cf][ks], acc[p * 4 + rf][cf], 0, 0, 0);
      __builtin_amdgcn_s_setprio(0);
      if (p == 0) {
        __builtin_amdgcn_sched_barrier(0);
        __builtin_amdgcn_s_barrier();  // phase lockstep; no counter drain
        __builtin_amdgcn_sched_barrier(0);
      }
    }
    __builtin_amdgcn_sched_barrier(0);
    if (t + 1 < nkt) {
      if (t + 2 < nkt)
        asm volatile("s_waitcnt vmcnt(6)" ::: "memory");
      else
        asm volatile("s_waitcnt vmcnt(0)" ::: "memory");
      __builtin_amdgcn_s_barrier();
      __builtin_amdgcn_sched_barrier(0);
    }
    slot = (slot == 2) ? 0 : slot + 1;
  }

#pragma unroll
  for (int i = 0; i < 8; ++i) {
    const int rbase = row0 + wm * 128 + (i >> 2) * 64 + (i & 3) * 16 + quad * 4;
#pragma unroll
    for (int j = 0; j < 2; ++j) {
      const int c = col0 + wn * 32 + j * 16 + lrow;
#pragma unroll
      for (int r = 0; r < 4; ++r) C[(size_t)(rbase + r) * ldc + c] = acc[i][j][r];
    }
  }
}

// =========================================================================
// GEMM1 fast (t2-tier fallback): energy = Eh*Fh^T + Eh*Fl^T + El*Fh^T.
// =========================================================================
__global__ __launch_bounds__(256) void gemm1_fast(const __bf16* __restrict__ Eh,
                                                  const __bf16* __restrict__ El,
                                                  const __bf16* __restrict__ Fh,
                                                  const __bf16* __restrict__ Fl,
                                                  float* __restrict__ C,
                                                  int row_base) {
  __shared__ __bf16 sAh[BM * BK], sAl[BM * BK], sBh[BN * BK], sBl[BN * BK];
  const int tid = threadIdx.x;
  const int wave = tid >> 6, lane = tid & 63;
  const int row0 = row_base + blockIdx.x * BM, col0 = blockIdx.y * BN;
  const int wm = wave >> 1, wn = wave & 1;
  const int lrow = lane & 15, quad = lane >> 4;

  f32x4_t acc[4][4];
#pragma unroll
  for (int i = 0; i < 4; i++)
#pragma unroll
    for (int j = 0; j < 4; j++) acc[i][j] = (f32x4_t){0.f, 0.f, 0.f, 0.f};

  for (int k0 = 0; k0 < D_DIM; k0 += BK) {
#pragma unroll
    for (int r = 0; r < 2; r++) {
      int c = (r * 4 + wave) * 64 + lane;
      int row = c >> 2;
      int ko = (c & 3) << 3;
      size_t ga = (size_t)(row0 + row) * D_DIM + k0 + ko;
      size_t gb = (size_t)(col0 + row) * D_DIM + k0 + ko;
      gload_lds16(Eh + ga, sAh + c * 8);
      gload_lds16(El + ga, sAl + c * 8);
      gload_lds16(Fh + gb, sBh + c * 8);
      gload_lds16(Fl + gb, sBl + c * 8);
    }
    __syncthreads();

    bf16x8_t ah[4], al[4], bh[4], bl[4];
#pragma unroll
    for (int i = 0; i < 4; i++) {
      int ra = (wm * 64 + i * 16 + lrow) * BK + quad * 8;
      ah[i] = *(const bf16x8_t*)(sAh + ra);
      al[i] = *(const bf16x8_t*)(sAl + ra);
      int rb = (wn * 64 + i * 16 + lrow) * BK + quad * 8;
      bh[i] = *(const bf16x8_t*)(sBh + rb);
      bl[i] = *(const bf16x8_t*)(sBl + rb);
    }
#pragma unroll
    for (int i = 0; i < 4; i++)
#pragma unroll
      for (int j = 0; j < 4; j++) {
        acc[i][j] = __builtin_amdgcn_mfma_f32_16x16x32_bf16(ah[i], bh[j], acc[i][j], 0, 0, 0);
        acc[i][j] = __builtin_amdgcn_mfma_f32_16x16x32_bf16(ah[i], bl[j], acc[i][j], 0, 0, 0);
        acc[i][j] = __builtin_amdgcn_mfma_f32_16x16x32_bf16(al[i], bh[j], acc[i][j], 0, 0, 0);
      }
    __syncthreads();
  }

#pragma unroll
  for (int i = 0; i < 4; i++) {
    int rbase = row0 + wm * 64 + i * 16 + quad * 4;
#pragma unroll
    for (int j = 0; j < 4; j++) {
      int c = col0 + wn * 64 + j * 16 + lrow;
#pragma unroll
      for (int r = 0; r < 4; r++) C[(size_t)(rbase + r) * M_FACTS + c] = acc[i][j][r];
    }
  }
}

// =========================================================================
// GEMM2 register-staged double buffer (t2-tier fallback).
// =========================================================================
__global__ __launch_bounds__(256) void gemm2_reg(const __bf16* __restrict__ Wb,
                                                 const __bf16* __restrict__ Ft,
                                                 float* __restrict__ O,
                                                 int out_row0) {
  __shared__ __bf16 sW[2][BM * BK];
  __shared__ __bf16 sF[2][BN * BK];
  const int tid = threadIdx.x;
  const int wave = tid >> 6, lane = tid & 63;
  const int row0 = blockIdx.x * BM;
  const int col0 = blockIdx.y * BN;
  const int wm = wave >> 1, wn = wave & 1;
  const int lrow = lane & 15, quad = lane >> 4;

  const int id0 = wave * 64 + lane;
  const int r0 = id0 >> 2, c0 = (id0 & 3) << 3;
  const int id1 = id0 + 256;
  const int r1 = id1 >> 2, c1 = (id1 & 3) << 3;

  const __bf16* gW = Wb + (size_t)row0 * M_FACTS;
  const __bf16* gF = Ft + (size_t)col0 * M_FACTS;

  f32x4_t acc[4][4];
#pragma unroll
  for (int i = 0; i < 4; i++)
#pragma unroll
    for (int j = 0; j < 4; j++) acc[i][j] = (f32x4_t){0.f, 0.f, 0.f, 0.f};

  bf16x8_t rW0, rW1, rF0, rF1;
  rW0 = *(const bf16x8_t*)(gW + (size_t)r0 * M_FACTS + c0);
  rW1 = *(const bf16x8_t*)(gW + (size_t)r1 * M_FACTS + c1);
  rF0 = *(const bf16x8_t*)(gF + (size_t)r0 * M_FACTS + c0);
  rF1 = *(const bf16x8_t*)(gF + (size_t)r1 * M_FACTS + c1);
  *(bf16x8_t*)(&sW[0][id0 * 8]) = rW0;
  *(bf16x8_t*)(&sW[0][id1 * 8]) = rW1;
  *(bf16x8_t*)(&sF[0][id0 * 8]) = rF0;
  *(bf16x8_t*)(&sF[0][id1 * 8]) = rF1;
  rW0 = *(const bf16x8_t*)(gW + (size_t)r0 * M_FACTS + BK + c0);
  rW1 = *(const bf16x8_t*)(gW + (size_t)r1 * M_FACTS + BK + c1);
  rF0 = *(const bf16x8_t*)(gF + (size_t)r0 * M_FACTS + BK + c0);
  rF1 = *(const bf16x8_t*)(gF + (size_t)r1 * M_FACTS + BK + c1);
  __syncthreads();

  const int NT = M_FACTS / BK;  // 256
  for (int it = 0; it < NT; it++) {
    const int cur = it & 1;
    bf16x8_t a[4], b[4];
#pragma unroll
    for (int i = 0; i < 4; i++) {
      a[i] = *(const bf16x8_t*)(&sW[cur][(wm * 64 + i * 16 + lrow) * BK + quad * 8]);
      b[i] = *(const bf16x8_t*)(&sF[cur][(wn * 64 + i * 16 + lrow) * BK + quad * 8]);
    }
#pragma unroll
    for (int i = 0; i < 4; i++)
#pragma unroll
      for (int j = 0; j < 4; j++)
        acc[i][j] = __builtin_amdgcn_mfma_f32_16x16x32_bf16(a[i], b[j], acc[i][j], 0, 0, 0);

    __syncthreads();
    if (it + 1 < NT) {
      const int nxt = cur ^ 1;
      *(bf16x8_t*)(&sW[nxt][id0 * 8]) = rW0;
      *(bf16x8_t*)(&sW[nxt][id1 * 8]) = rW1;
      *(bf16x8_t*)(&sF[nxt][id0 * 8]) = rF0;
      *(bf16x8_t*)(&sF[nxt][id1 * 8]) = rF1;
      if (it + 2 < NT) {
        const int ko = (it + 2) * BK;
        rW0 = *(const bf16x8_t*)(gW + (size_t)r0 * M_FACTS + ko + c0);
        rW1 = *(const bf16x8_t*)(gW + (size_t)r1 * M_FACTS + ko + c1);
        rF0 = *(const bf16x8_t*)(gF + (size_t)r0 * M_FACTS + ko + c0);
        rF1 = *(const bf16x8_t*)(gF + (size_t)r1 * M_FACTS + ko + c1);
      }
      __syncthreads();
    }
  }

#pragma unroll
  for (int i = 0; i < 4; i++) {
    int rbase = out_row0 + row0 + wm * 64 + i * 16 + quad * 4;
#pragma unroll
    for (int j = 0; j < 4; j++) {
      int c = col0 + wn * 64 + j * 16 + lrow;
#pragma unroll
      for (int r = 0; r < 4; r++) O[(size_t)(rbase + r) * D_DIM + c] = acc[i][j][r];
    }
  }
}

// GEMM2 mid fallback: A = W fp32 (convert in staging), B = Ft via async.
__global__ __launch_bounds__(256) void gemm2_mid(const float* __restrict__ W,
                                                 const __bf16* __restrict__ Ft,
                                                 float* __restrict__ O) {
  __shared__ __bf16 sW[BM * BK], sF[BN * BK];
  const int tid = threadIdx.x;
  const int wave = tid >> 6, lane = tid & 63;
  const int row0 = blockIdx.x * BM, col0 = blockIdx.y * BN;
  const int wm = wave >> 1, wn = wave & 1;
  const int lrow = lane & 15, quad = lane >> 4;

  f32x4_t acc[4][4];
#pragma unroll
  for (int i = 0; i < 4; i++)
#pragma unroll
    for (int j = 0; j < 4; j++) acc[i][j] = (f32x4_t){0.f, 0.f, 0.f, 0.f};

  for (int k0 = 0; k0 < M_FACTS; k0 += BK) {
#pragma unroll
    for (int r = 0; r < 2; r++) {
      int c = (r * 4 + wave) * 64 + lane;
      int row = c >> 2;
      int ko = (c & 3) << 3;
      gload_lds16(Ft + (size_t)(col0 + row) * M_FACTS + k0 + ko, sF + c * 8);
    }
#pragma unroll
    for (int it = 0; it < 4; it++) {
      int flat = it * 256 + tid;
      int r = flat >> 3, q = flat & 7;
      float4 v = *(const float4*)(W + (size_t)(row0 + r) * M_FACTS + k0 + q * 4);
      bf16x4_t h;
      h[0] = (__bf16)v.x;
      h[1] = (__bf16)v.y;
      h[2] = (__bf16)v.z;
      h[3] = (__bf16)v.w;
      *(bf16x4_t*)(sW + r * BK + q * 4) = h;
    }
    __syncthreads();

    bf16x8_t a[4], b[4];
#pragma unroll
    for (int i = 0; i < 4; i++) {
      a[i] = *(const bf16x8_t*)(sW + (wm * 64 + i * 16 + lrow) * BK + quad * 8);
      b[i] = *(const bf16x8_t*)(sF + (wn * 64 + i * 16 + lrow) * BK + quad * 8);
    }
#pragma unroll
    for (int i = 0; i < 4; i++)
#pragma unroll
      for (int j = 0; j < 4; j++)
        acc[i][j] = __builtin_amdgcn_mfma_f32_16x16x32_bf16(a[i], b[j], acc[i][j], 0, 0, 0);
    __syncthreads();
  }

#pragma unroll
  for (int i = 0; i < 4; i++) {
    int rbase = row0 + wm * 64 + i * 16 + quad * 4;
#pragma unroll
    for (int j = 0; j < 4; j++) {
      int c = col0 + wn * 64 + j * 16 + lrow;
#pragma unroll
      for (int r = 0; r < 4; r++) O[(size_t)(rbase + r) * D_DIM + c] = acc[i][j][r];
    }
  }
}

// =========================================================================
// Softmax (optionally emitting bf16 copy of weights)
// =========================================================================
template <bool EMIT_BF16>
__global__ __launch_bounds__(256) void softmax_rows_t(float* __restrict__ W,
                                                      __bf16* __restrict__ Wb) {
  __shared__ float red[8];
  const int tid = threadIdx.x;
  float* p = W + (size_t)blockIdx.x * M_FACTS;

  float4 v[8];
  float mx = -3.4e38f;
#pragma unroll
  for (int i = 0; i < 8; i++) {
    v[i] = *(const float4*)(p + (size_t)(i * 256 + tid) * 4);
    mx = fmaxf(mx, fmaxf(fmaxf(v[i].x, v[i].y), fmaxf(v[i].z, v[i].w)));
  }
#pragma unroll
  for (int off = 32; off >= 1; off >>= 1) mx = fmaxf(mx, __shfl_xor(mx, off));
  const int wave = tid >> 6, lane = tid & 63;
  if (lane == 0) red[wave] = mx;
  __syncthreads();
  mx = fmaxf(fmaxf(red[0], red[1]), fmaxf(red[2], red[3]));

  float s = 0.f;
#pragma unroll
  for (int i = 0; i < 8; i++) {
    v[i].x = __expf(v[i].x - mx);
    v[i].y = __expf(v[i].y - mx);
    v[i].z = __expf(v[i].z - mx);
    v[i].w = __expf(v[i].w - mx);
    s += v[i].x + v[i].y + v[i].z + v[i].w;
  }
#pragma unroll
  for (int off = 32; off >= 1; off >>= 1) s += __shfl_xor(s, off);
  if (lane == 0) red[4 + wave] = s;
  __syncthreads();
  s = red[4] + red[5] + red[6] + red[7];
  float inv = 1.0f / s;
  __bf16* pb = EMIT_BF16 ? (Wb + (size_t)blockIdx.x * M_FACTS) : nullptr;
#pragma unroll
  for (int i = 0; i < 8; i++) {
    v[i].x *= inv;
    v[i].y *= inv;
    v[i].z *= inv;
    v[i].w *= inv;
    *(float4*)(p + (size_t)(i * 256 + tid) * 4) = v[i];
    if (EMIT_BF16) {
      bf16x4_t h;
      h[0] = (__bf16)v[i].x;
      h[1] = (__bf16)v[i].y;
      h[2] = (__bf16)v[i].z;
      h[3] = (__bf16)v[i].w;
      *(bf16x4_t*)(pb + (size_t)(i * 256 + tid) * 4) = h;
    }
  }
}

// =========================================================================
// Lowest-tier fallback kernels (ws < 80 MiB)
// =========================================================================
__global__ __launch_bounds__(256) void gemm1_energy(const float* __restrict__ A,
                                                    const float* __restrict__ B,
                                                    float* __restrict__ C) {
  __shared__ __align__(16) __bf16 sAh[BM * PADK];
  __shared__ __align__(16) __bf16 sAl[BM * PADK];
  __shared__ __align__(16) __bf16 sBh[BN * PADK];
  __shared__ __align__(16) __bf16 sBl[BN * PADK];

  const int tid = threadIdx.x;
  const int row0 = blockIdx.x * BM, col0 = blockIdx.y * BN;
  const int wave = tid >> 6, lane = tid & 63;
  const int wm = wave >> 1, wn = wave & 1;
  const int lrow = lane & 15, quad = lane >> 4;

  f32x4_t acc[4][4];
#pragma unroll
  for (int i = 0; i < 4; i++)
#pragma unroll
    for (int j = 0; j < 4; j++) acc[i][j] = (f32x4_t){0.f, 0.f, 0.f, 0.f};

  for (int k0 = 0; k0 < D_DIM; k0 += BK) {
    __syncthreads();
#pragma unroll
    for (int it = 0; it < 4; it++) {
      int flat = it * 256 + tid;
      int r = flat >> 3, kq = flat & 7;
      float4 va = *(const float4*)(A + (size_t)(row0 + r) * D_DIM + k0 + kq * 4);
      float4 vb = *(const float4*)(B + (size_t)(col0 + r) * D_DIM + k0 + kq * 4);
      float fa[4] = {va.x, va.y, va.z, va.w};
      float fb[4] = {vb.x, vb.y, vb.z, vb.w};
      bf16x4_t ah, al, bh, bl;
#pragma unroll
      for (int q = 0; q < 4; q++) {
        __bf16 h = (__bf16)fa[q];
        ah[q] = h;
        al[q] = (__bf16)(fa[q] - (float)h);
        __bf16 g = (__bf16)fb[q];
        bh[q] = g;
        bl[q] = (__bf16)(fb[q] - (float)g);
      }
      *(bf16x4_t*)(sAh + r * PADK + kq * 4) = ah;
      *(bf16x4_t*)(sAl + r * PADK + kq * 4) = al;
      *(bf16x4_t*)(sBh + r * PADK + kq * 4) = bh;
      *(bf16x4_t*)(sBl + r * PADK + kq * 4) = bl;
    }
    __syncthreads();

    bf16x8_t a_h[4], a_l[4], b_h[4], b_l[4];
#pragma unroll
    for (int i = 0; i < 4; i++) {
      int ra = wm * 64 + i * 16 + lrow;
      a_h[i] = *(const bf16x8_t*)(sAh + ra * PADK + quad * 8);
      a_l[i] = *(const bf16x8_t*)(sAl + ra * PADK + quad * 8);
      int rb = wn * 64 + i * 16 + lrow;
      b_h[i] = *(const bf16x8_t*)(sBh + rb * PADK + quad * 8);
      b_l[i] = *(const bf16x8_t*)(sBl + rb * PADK + quad * 8);
    }
#pragma unroll
    for (int i = 0; i < 4; i++)
#pragma unroll
      for (int j = 0; j < 4; j++) {
        acc[i][j] = __builtin_amdgcn_mfma_f32_16x16x32_bf16(a_h[i], b_h[j], acc[i][j], 0, 0, 0);
        acc[i][j] = __builtin_amdgcn_mfma_f32_16x16x32_bf16(a_h[i], b_l[j], acc[i][j], 0, 0, 0);
        acc[i][j] = __builtin_amdgcn_mfma_f32_16x16x32_bf16(a_l[i], b_h[j], acc[i][j], 0, 0, 0);
      }
  }

#pragma unroll
  for (int i = 0; i < 4; i++) {
    int rbase = row0 + wm * 64 + i * 16 + quad * 4;
#pragma unroll
    for (int j = 0; j < 4; j++) {
      int c = col0 + wn * 64 + j * 16 + lrow;
#pragma unroll
      for (int r = 0; r < 4; r++) C[(size_t)(rbase + r) * M_FACTS + c] = acc[i][j][r];
    }
  }
}

__global__ __launch_bounds__(256) void gemm2_out(const float* __restrict__ W,
                                                 const float* __restrict__ F,
                                                 float* __restrict__ O) {
  __shared__ __align__(16) __bf16 sW[BM * PADK];
  __shared__ __align__(16) __bf16 sFt[BN * PADK];

  const int tid = threadIdx.x;
  const int row0 = blockIdx.x * BM, col0 = blockIdx.y * BN;
  const int wave = tid >> 6, lane = tid & 63;
  const int wm = wave >> 1, wn = wave & 1;
  const int lrow = lane & 15, quad = lane >> 4;

  f32x4_t acc[4][4];
#pragma unroll
  for (int i = 0; i < 4; i++)
#pragma unroll
    for (int j = 0; j < 4; j++) acc[i][j] = (f32x4_t){0.f, 0.f, 0.f, 0.f};

  for (int k0 = 0; k0 < M_FACTS; k0 += BK) {
    __syncthreads();
#pragma unroll
    for (int it = 0; it < 4; it++) {
      int flat = it * 256 + tid;
      int r = flat >> 3, kq = flat & 7;
      float4 v = *(const float4*)(W + (size_t)(row0 + r) * M_FACTS + k0 + kq * 4);
      bf16x4_t h;
      h[0] = (__bf16)v.x;
      h[1] = (__bf16)v.y;
      h[2] = (__bf16)v.z;
      h[3] = (__bf16)v.w;
      *(bf16x4_t*)(sW + r * PADK + kq * 4) = h;
    }
#pragma unroll
    for (int it = 0; it < 4; it++) {
      int flat = it * 256 + tid;
      int m = flat >> 5, dq = flat & 31;
      float4 v = *(const float4*)(F + (size_t)(k0 + m) * D_DIM + col0 + dq * 4);
      sFt[(dq * 4 + 0) * PADK + m] = (__bf16)v.x;
      sFt[(dq * 4 + 1) * PADK + m] = (__bf16)v.y;
      sFt[(dq * 4 + 2) * PADK + m] = (__bf16)v.z;
      sFt[(dq * 4 + 3) * PADK + m] = (__bf16)v.w;
    }
    __syncthreads();

    bf16x8_t a[4], b[4];
#pragma unroll
    for (int i = 0; i < 4; i++) {
      a[i] = *(const bf16x8_t*)(sW + (wm * 64 + i * 16 + lrow) * PADK + quad * 8);
      b[i] = *(const bf16x8_t*)(sFt + (wn * 64 + i * 16 + lrow) * PADK + quad * 8);
    }
#pragma unroll
    for (int i = 0; i < 4; i++)
#pragma unroll
      for (int j = 0; j < 4; j++)
        acc[i][j] = __builtin_amdgcn_mfma_f32_16x16x32_bf16(a[i], b[j], acc[i][j], 0, 0, 0);
  }

#pragma unroll
  for (int i = 0; i < 4; i++) {
    int rbase = row0 + wm * 64 + i * 16 + quad * 4;
#pragma unroll
    for (int j = 0; j < 4; j++) {
      int c = col0 + wn * 64 + j * 16 + lrow;
#pragma unroll
      for (int r = 0; r < 4; r++) O[(size_t)(rbase + r) * D_DIM + c] = acc[i][j][r];
    }
  }
}

// =========================================================================
extern "C" void kernel_launch(void* const* d_in, const int* in_sizes, int n_in,
                              void* d_out, int out_size, void* d_ws, size_t ws_size,
                              hipStream_t stream) {
  const float* E = (const float*)d_in[0];  // [N, D]
  const float* F = (const float*)d_in[1];  // [M, D]
  float* outputs = (float*)d_out;                           // [N, D]
  float* weights = (float*)d_out + (size_t)N_ROWS * D_DIM;  // [N, M]

  const size_t MB = 1ull << 20;
  char* ws = (char*)d_ws;

  const bool t1 = ws_size >= 144 * MB;
  const bool t2 = !t1 && ws_size >= 80 * MB;
  const bool hasFtOnly = !t1 && !t2 && ws_size >= 16 * MB;

  if (t1) {
    // Layout: Ft 0-16MB | A2 16-64MB | B2 64-112MB | Wb 16-144MB (aliases
    // dead A2/B2 after gemm1).
    __bf16* Ft = (__bf16*)(ws + 0 * MB);
    __bf16* A2 = (__bf16*)(ws + 16 * MB);
    __bf16* B2 = (__bf16*)(ws + 64 * MB);
    __bf16* Wb = (__bf16*)(ws + 16 * MB);

    transpose_f_bf16<<<dim3(M_FACTS / 64, D_DIM / 64), 256, 0, stream>>>(F, Ft);
    split_concat_E<<<dim3((N_ROWS * D_DIM) / 1024), 256, 0, stream>>>(E, A2);
    split_concat_F<<<dim3((M_FACTS * D_DIM) / 1024), 256, 0, stream>>>(F, B2);

    // gemm1: ONE bf16 GEMM, K=3072 (round-6 kernel, 364-368us stable).
    gemm_pipe<4><<<dim3(N_ROWS / 256, M_FACTS / 256), 512, 0, stream>>>(
        A2, B2, weights, 3072, 3072, 3072, M_FACTS);

    softmax_rows_t<true><<<dim3(N_ROWS), 256, 0, stream>>>(weights, Wb);

    // gemm2: round-3 ring kernel, grid (32,8) = 256 blocks = 1/CU.
    // Budget-implied ~141us at this exact call site (passed refcheck R3)
    // vs gemm2_reg's measured 205us.
    gemm_ring<<<dim3(N_ROWS / 256, D_DIM / 128), 512, 0, stream>>>(
        Wb, Ft, outputs, M_FACTS, M_FACTS, M_FACTS, D_DIM);
  } else if (t2) {
    __bf16* Ft = (__bf16*)(ws + 0 * MB);
    __bf16* Eh = (__bf16*)(ws + 16 * MB);
    __bf16* El = (__bf16*)(ws + 32 * MB);
    __bf16* Fh = (__bf16*)(ws + 48 * MB);
    __bf16* Fl = (__bf16*)(ws + 64 * MB);
    __bf16* Wb = (__bf16*)(ws + 16 * MB);

    transpose_f_bf16<<<dim3(M_FACTS / 64, D_DIM / 64), 256, 0, stream>>>(F, Ft);
    split_hi_lo<<<dim3((N_ROWS * D_DIM) / 1024), 256, 0, stream>>>(E, Eh, El);
    split_hi_lo<<<dim3((M_FACTS * D_DIM) / 1024), 256, 0, stream>>>(F, Fh, Fl);
    gemm1_fast<<<dim3(N_ROWS / BM, M_FACTS / BN), 256, 0, stream>>>(Eh, El, Fh, Fl,
                                                                    weights, 0);
    const int HALF = N_ROWS / 2;
    for (int h = 0; h < 2; h++) {
      float* Wchunk = weights + (size_t)h * HALF * M_FACTS;
      softmax_rows_t<true><<<dim3(HALF), 256, 0, stream>>>(Wchunk, Wb);
      gemm2_reg<<<dim3(HALF / BM, D_DIM / BN), 256, 0, stream>>>(Wb, Ft, outputs, h * HALF);
    }
  } else {
    __bf16* Ft = (__bf16*)ws;  // 16 MiB
    if (hasFtOnly) {
      transpose_f_bf16<<<dim3(M_FACTS / 64, D_DIM / 64), 256, 0, stream>>>(F, Ft);
    }
    gemm1_energy<<<dim3(N_ROWS / BM, M_FACTS / BN), 256, 0, stream>>>(E, F, weights);
    softmax_rows_t<false><<<dim3(N_ROWS), 256, 0, stream>>>(weights, nullptr);
    if (hasFtOnly) {
      gemm2_mid<<<dim3(N_ROWS / BM, D_DIM / BN), 256, 0, stream>>>(weights, Ft, outputs);
    } else {
      gemm2_out<<<dim3(N_ROWS / BM, D_DIM / BN), 256, 0, stream>>>(weights, F, outputs);
    }
  }
}